// Round 3
// baseline (1473.707 us; speedup 1.0000x reference)
//
#include <hip/hip_runtime.h>
#include <hip/hip_fp16.h>

#define B_  256
#define T_  2048
#define D_  128
#define H_  128
#define CH  32
#define NCH (T_ / CH)

#define NLOG2E  (-1.4426950408889634f)   // i,f,o rows: sigm(x)=rcp(1+exp2(x*NLOG2E))
#define LOG2E2  ( 2.8853900817779268f)   // g rows:    tanh(x)=1-2*rcp(1+exp2(x*LOG2E2))

typedef __attribute__((ext_vector_type(8))) _Float16 half8v;
typedef __attribute__((ext_vector_type(4))) float    floatx4;

static __device__ __forceinline__ unsigned pkh(float a, float b) {
  return __builtin_bit_cast(unsigned, __builtin_amdgcn_cvt_pkrtz(a, b));
}
static __device__ __forceinline__ float h2f_lo(unsigned u) {
  return __half2float(__ushort_as_half((unsigned short)(u & 0xffffu)));
}
static __device__ __forceinline__ float h2f_hi(unsigned u) {
  return __half2float(__ushort_as_half((unsigned short)(u >> 16)));
}

// One block per batch element (256 blocks, 1/CU). 1024 threads = 16 waves
// (4/SIMD). Per-wave register budget 128 (launch_bounds 1024,4): wa 32 +
// wb 32 + hfr 16 + acc 8 + misc ~ 115 -> no AGPR shuttling in the hot loop.
//
// Recurrence: gates^T = Whh_s @ h^T via MFMA. Whh rows are PERMUTED so wave
// wv's two M-tiles hold, for its 8 units (j = wv*8 + (r>>1)), gates (i,f) in
// tile 0 and (g,o) in tile 1, row-within-tile r: gate = p*2 + (r&1). With the
// m89 D-layout (col=lane&15, row=quad*4+reg), lane (quad, n<2) then owns all
// 4 gate preacts of unit j = wv*8 + quad*2 + n in regs a0[2n..],a1[2n..].
// h is replicated into B cols 0,1 (masked 8-lane ds_read_b128 -> no broadcast
// charge). Nonlinearity scales folded into Whh/Wih/bias at load.
__global__ __launch_bounds__(1024, 4) void lstm_mfma2(
    const float* __restrict__ x,   const float* __restrict__ Wih,
    const float* __restrict__ Whh, const float* __restrict__ bih,
    const float* __restrict__ bhh, const float* __restrict__ Wo,
    const float* __restrict__ bo,  float* __restrict__ out)
{
  __shared__ unsigned       xs[CH][68];          // x chunk, f16 pairs (+4 pad)
  __shared__ unsigned short xgf[CH][4 * H_];     // xg preact (scaled+biased), f16, [t][j*4+gt]
  __shared__ __align__(16) unsigned hbuf[2][64]; // h ping-pong, f16 pairs

  const int tid  = threadIdx.x;
  const int b    = blockIdx.x;
  const int lane = tid & 63;
  const int wv   = tid >> 6;                     // 0..15
  const int quad = (lane >> 4);
  const int m16  = lane & 15;

  // ---- Whh A-fragments (permuted rows), pre-scaled, persistent (32 regs)
  uint4 wa[2][4];
  #pragma unroll
  for (int p = 0; p < 2; ++p) {
    int gt  = p * 2 + (m16 & 1);
    int row = gt * H_ + wv * 8 + (m16 >> 1);
    float s = (gt == 2) ? LOG2E2 : NLOG2E;
    const float4* pr = (const float4*)(Whh + (size_t)row * H_);
    #pragma unroll
    for (int kf = 0; kf < 4; ++kf) {
      float4 f0 = pr[kf * 8 + quad * 2];
      float4 f1 = pr[kf * 8 + quad * 2 + 1];
      uint4 u;
      u.x = pkh(f0.x * s, f0.y * s);  u.y = pkh(f0.z * s, f0.w * s);
      u.z = pkh(f1.x * s, f1.y * s);  u.w = pkh(f1.z * s, f1.w * s);
      wa[p][kf] = u;
    }
  }

  // ---- Wih B-fragments (32 regs): wave owns gate cols [wv*32, wv*32+32)
  uint4 wb[2][4];
  float bv[2];
  #pragma unroll
  for (int nt = 0; nt < 2; ++nt) {
    int gcol = wv * 32 + nt * 16 + m16;
    float sW = ((gcol >> 7) == 2) ? LOG2E2 : NLOG2E;   // uniform per (wv,nt)
    const float4* pr = (const float4*)(Wih + (size_t)gcol * D_);
    #pragma unroll
    for (int kf = 0; kf < 4; ++kf) {
      float4 f0 = pr[kf * 8 + quad * 2];
      float4 f1 = pr[kf * 8 + quad * 2 + 1];
      uint4 u;
      u.x = pkh(f0.x * sW, f0.y * sW);  u.y = pkh(f0.z * sW, f0.w * sW);
      u.z = pkh(f1.x * sW, f1.y * sW);  u.w = pkh(f1.z * sW, f1.w * sW);
      wb[nt][kf] = u;
    }
    bv[nt] = (bih[gcol] + bhh[gcol]) * sW;
  }

  if (tid < 128) hbuf[tid >> 6][tid & 63] = 0u;
  uint4 hfr[4] = {{0,0,0,0},{0,0,0,0},{0,0,0,0},{0,0,0,0}};
  float c = 0.0f;
  __syncthreads();

  const float* xb = x + (size_t)b * T_ * D_;

  for (int ch = 0; ch < NCH; ++ch) {
    // ---- stage x chunk (16 KB) as f16 pairs: 1024 float4, one per thread
    {
      float4 v = ((const float4*)(xb + (size_t)ch * CH * D_))[tid];
      int t  = tid >> 5;
      int kp = (tid & 31) * 2;
      xs[t][kp]     = pkh(v.x, v.y);
      xs[t][kp + 1] = pkh(v.z, v.w);
    }
    __syncthreads();

    // ---- xg chunk: [32 t] x [512 g] = xs @ Wih_s^T (+ scaled bias), f16 out
    {
      floatx4 acc[2][2] = {{{0,0,0,0},{0,0,0,0}},{{0,0,0,0},{0,0,0,0}}};
      #pragma unroll
      for (int kf = 0; kf < 4; ++kf) {
        half8v af[2];
        #pragma unroll
        for (int mt = 0; mt < 2; ++mt)
          af[mt] = __builtin_bit_cast(half8v,
                     *(const uint4*)&xs[mt * 16 + m16][kf * 16 + quad * 4]);
        #pragma unroll
        for (int mt = 0; mt < 2; ++mt)
          #pragma unroll
          for (int nt = 0; nt < 2; ++nt)
            acc[mt][nt] = __builtin_amdgcn_mfma_f32_16x16x32_f16(
                af[mt], __builtin_bit_cast(half8v, wb[nt][kf]), acc[mt][nt], 0, 0, 0);
      }
      #pragma unroll
      for (int mt = 0; mt < 2; ++mt)
        #pragma unroll
        for (int nt = 0; nt < 2; ++nt) {
          int gcol = wv * 32 + nt * 16 + m16;
          int jc = gcol & 127, gt = gcol >> 7;
          #pragma unroll
          for (int r = 0; r < 4; ++r)
            xgf[mt * 16 + quad * 4 + r][jc * 4 + gt] =
                __half_as_ushort(__float2half(acc[mt][nt][r] + bv[nt]));
        }
    }
    __syncthreads();

    // ---- 32 recurrence steps
    #pragma unroll 2
    for (int tt = 0; tt < CH; ++tt) {
      const int rp = tt & 1;                       // CH even -> phase is tt&1
      unsigned long long xv = 0ull;
      if (m16 < 2) {
        int jl = wv * 8 + quad * 2 + m16;
        xv = *(const unsigned long long*)&xgf[tt][jl * 4];
        #pragma unroll
        for (int kf = 0; kf < 4; ++kf)
          hfr[kf] = *(const uint4*)&hbuf[rp][kf * 16 + quad * 4];
      }
      floatx4 a0 = {0,0,0,0}, a1 = {0,0,0,0};
      #pragma unroll
      for (int kf = 0; kf < 4; ++kf) {
        half8v hb = __builtin_bit_cast(half8v, hfr[kf]);
        a0 = __builtin_amdgcn_mfma_f32_16x16x32_f16(
                 __builtin_bit_cast(half8v, wa[0][kf]), hb, a0, 0, 0, 0);
        a1 = __builtin_amdgcn_mfma_f32_16x16x32_f16(
                 __builtin_bit_cast(half8v, wa[1][kf]), hb, a1, 0, 0, 0);
      }
      if (m16 < 2) {
        const int n  = m16;
        const int jl = wv * 8 + quad * 2 + n;
        unsigned xlo = (unsigned)xv, xhi = (unsigned)(xv >> 32);
        float pi = (n ? a0[2] : a0[0]) + h2f_lo(xlo);
        float pf = (n ? a0[3] : a0[1]) + h2f_hi(xlo);
        float pg = (n ? a1[2] : a1[0]) + h2f_lo(xhi);
        float po = (n ? a1[3] : a1[1]) + h2f_hi(xhi);
        float gi = __builtin_amdgcn_rcpf(1.0f + __builtin_amdgcn_exp2f(pi));
        float gf = __builtin_amdgcn_rcpf(1.0f + __builtin_amdgcn_exp2f(pf));
        float go = __builtin_amdgcn_rcpf(1.0f + __builtin_amdgcn_exp2f(po));
        float gg = 1.0f - 2.0f * __builtin_amdgcn_rcpf(1.0f + __builtin_amdgcn_exp2f(pg));
        c = gf * c + gi * gg;
        float tc = 1.0f - 2.0f * __builtin_amdgcn_rcpf(
                       1.0f + __builtin_amdgcn_exp2f(c * LOG2E2));
        float h = go * tc;
        ((unsigned short*)hbuf[rp ^ 1])[jl] = __half_as_ushort(__float2half(h));
      }
      __syncthreads();
    }
  }

  // ---- out = h_last @ Wo^T + bo   (h_last in hbuf[0]: last step wrote buf 0)
  if (tid < H_) {
    float acc = bo[tid];
    const float4* wr = (const float4*)(Wo + (size_t)tid * H_);
    const uint2* hp = (const uint2*)hbuf[0];
    #pragma unroll
    for (int k4 = 0; k4 < 32; ++k4) {
      float4 w  = wr[k4];
      uint2  hu = hp[k4];
      acc += w.x * h2f_lo(hu.x) + w.y * h2f_hi(hu.x)
           + w.z * h2f_lo(hu.y) + w.w * h2f_hi(hu.y);
    }
    out[(size_t)b * H_ + tid] = acc;
  }
}

extern "C" void kernel_launch(void* const* d_in, const int* in_sizes, int n_in,
                              void* d_out, int out_size, void* d_ws, size_t ws_size,
                              hipStream_t stream) {
  (void)in_sizes; (void)n_in; (void)d_ws; (void)ws_size; (void)out_size;
  const float* x   = (const float*)d_in[0];
  const float* Wih = (const float*)d_in[1];
  const float* Whh = (const float*)d_in[2];
  const float* bih = (const float*)d_in[3];
  const float* bhh = (const float*)d_in[4];
  const float* Wo  = (const float*)d_in[5];
  const float* bo  = (const float*)d_in[6];
  lstm_mfma2<<<B_, 1024, 0, stream>>>(x, Wih, Whh, bih, bhh, Wo, bo, (float*)d_out);
}

// Round 4
// 1279.932 us; speedup vs baseline: 1.1514x; 1.1514x over previous
//
#include <hip/hip_runtime.h>
#include <hip/hip_fp16.h>

#define B_  256
#define T_  2048
#define D_  128
#define H_  128
#define CH  32
#define NCH (T_ / CH)
#define XGP (4 * H_ + 8)                 // xgf padded row: +16B breaks 4-way bank conflict

#define NLOG2E  (-1.4426950408889634f)   // i,f,o rows: sigm(x)=rcp(1+exp2(x*NLOG2E))
#define LOG2E2  ( 2.8853900817779268f)   // g rows:    tanh(x)=1-2*rcp(1+exp2(x*LOG2E2))

typedef __attribute__((ext_vector_type(8))) _Float16 half8v;
typedef __attribute__((ext_vector_type(4))) float    floatx4;

static __device__ __forceinline__ unsigned pkh(float a, float b) {
  return __builtin_bit_cast(unsigned, __builtin_amdgcn_cvt_pkrtz(a, b));
}
static __device__ __forceinline__ float h2f_lo(unsigned u) {
  return __half2float(__ushort_as_half((unsigned short)(u & 0xffffu)));
}
static __device__ __forceinline__ float h2f_hi(unsigned u) {
  return __half2float(__ushort_as_half((unsigned short)(u >> 16)));
}
// select v[n] for n in [0,4) -> 3 v_cndmask
#define SEL4(v, n) (((n) & 2) ? (((n) & 1) ? (v)[3] : (v)[2]) \
                              : (((n) & 1) ? (v)[1] : (v)[0]))

// One block per batch element (256 blocks = 1/CU). 512 threads = 8 waves
// (2/SIMD). amdgpu_waves_per_eu(2,2): grid is 1 block/CU so occupancy >2
// waves/EU is unreachable -- give each wave the full 256-VGPR budget so the
// persistent Whh/Wih fragments (128 regs) live in arch VGPRs with NO
// accvgpr shuttling in the 2048-iteration recurrence (R1-R3 bottleneck).
__global__ __attribute__((amdgpu_flat_work_group_size(512, 512),
                          amdgpu_waves_per_eu(2, 2)))
void lstm_mfma3(
    const float* __restrict__ x,   const float* __restrict__ Wih,
    const float* __restrict__ Whh, const float* __restrict__ bih,
    const float* __restrict__ bhh, const float* __restrict__ Wo,
    const float* __restrict__ bo,  float* __restrict__ out)
{
  __shared__ unsigned       xs[CH][68];          // x chunk, f16 pairs (+4 pad)
  __shared__ unsigned short xgf[CH][XGP];        // xg preact (scaled+biased), f16
  __shared__ __align__(16) unsigned hbuf[2][64]; // h ping-pong, f16 pairs

  const int tid  = threadIdx.x;
  const int b    = blockIdx.x;
  const int lane = tid & 63;
  const int wv   = tid >> 6;
  const int quad = lane >> 4;
  const int m16  = lane & 15;

  // ---- Whh A-fragments, pre-scaled, persistent: wa[mt][kf] = 8 f16 of
  // Whh_s[mt*128+wv*16+m16][kf*32+quad*8 .. +7]
  uint4 wa[4][4];
  #pragma unroll
  for (int mt = 0; mt < 4; ++mt) {
    float s = (mt == 2) ? LOG2E2 : NLOG2E;
    const float4* p = (const float4*)(Whh + (size_t)(mt * 128 + wv * 16 + m16) * H_);
    #pragma unroll
    for (int kf = 0; kf < 4; ++kf) {
      float4 f0 = p[kf * 8 + quad * 2];
      float4 f1 = p[kf * 8 + quad * 2 + 1];
      uint4 u;
      u.x = pkh(f0.x * s, f0.y * s);  u.y = pkh(f0.z * s, f0.w * s);
      u.z = pkh(f1.x * s, f1.y * s);  u.w = pkh(f1.z * s, f1.w * s);
      wa[mt][kf] = u;
    }
  }

  // ---- Wih B-fragments for the input GEMM, pre-scaled by gate type (= wv>>1)
  const float sW = ((wv >> 1) == 2) ? LOG2E2 : NLOG2E;
  uint4 wb[4][4];
  float bv[4];
  #pragma unroll
  for (int nt = 0; nt < 4; ++nt) {
    int gcol = wv * 64 + nt * 16 + m16;
    const float4* p = (const float4*)(Wih + (size_t)gcol * D_);
    #pragma unroll
    for (int kf = 0; kf < 4; ++kf) {
      float4 f0 = p[kf * 8 + quad * 2];
      float4 f1 = p[kf * 8 + quad * 2 + 1];
      uint4 u;
      u.x = pkh(f0.x * sW, f0.y * sW);  u.y = pkh(f0.z * sW, f0.w * sW);
      u.z = pkh(f1.x * sW, f1.y * sW);  u.w = pkh(f1.z * sW, f1.w * sW);
      wb[nt][kf] = u;
    }
    bv[nt] = (bih[gcol] + bhh[gcol]) * sW;
  }

  if (tid < 128) hbuf[tid >> 6][tid & 63] = 0u;
  uint4 hfr[4] = {{0,0,0,0},{0,0,0,0},{0,0,0,0},{0,0,0,0}};
  floatx4 zf = {0.f, 0.f, 0.f, 0.f};             // persistent MFMA C-init
  float c = 0.0f;
  __syncthreads();

  const float* xb = x + (size_t)b * T_ * D_;

  for (int ch = 0; ch < NCH; ++ch) {
    // ---- stage x chunk (16 KB) as f16 pairs
    const float4* xsrc = (const float4*)(xb + (size_t)ch * CH * D_);
    #pragma unroll
    for (int i = 0; i < 2; ++i) {
      int fi = i * 512 + tid;
      float4 v = xsrc[fi];
      int t  = fi >> 5;
      int kp = (fi & 31) * 2;
      xs[t][kp]     = pkh(v.x, v.y);
      xs[t][kp + 1] = pkh(v.z, v.w);
    }
    __syncthreads();

    // ---- xg chunk: [32 t] x [512 g] = xs @ Wih_s^T (+ scaled bias), f16 out
    #pragma unroll
    for (int mt = 0; mt < 2; ++mt) {
      half8v af[4];
      #pragma unroll
      for (int kf = 0; kf < 4; ++kf)
        af[kf] = __builtin_bit_cast(half8v,
                   *(const uint4*)&xs[mt * 16 + m16][kf * 16 + quad * 4]);
      #pragma unroll
      for (int nt = 0; nt < 4; ++nt) {
        floatx4 acc = zf;
        #pragma unroll
        for (int kf = 0; kf < 4; ++kf)
          acc = __builtin_amdgcn_mfma_f32_16x16x32_f16(
              af[kf], __builtin_bit_cast(half8v, wb[nt][kf]), acc, 0, 0, 0);
        int gcol = wv * 64 + nt * 16 + m16;
        int jc   = gcol & 127, gt = gcol >> 7;
        #pragma unroll
        for (int r = 0; r < 4; ++r) {
          int trow = mt * 16 + quad * 4 + r;
          xgf[trow][jc * 4 + gt] =
              __half_as_ushort(__float2half(acc[r] + bv[nt]));
        }
      }
    }
    __syncthreads();

    // ---- 32 recurrence steps
    #pragma unroll 2
    for (int tt = 0; tt < CH; ++tt) {
      const int rp = tt & 1;
      unsigned long long xv = 0ull;
      if (m16 < 4) {
        xv = *(const unsigned long long*)&xgf[tt][(wv * 16 + quad * 4 + m16) * 4];
        #pragma unroll
        for (int kf = 0; kf < 4; ++kf)
          hfr[kf] = *(const uint4*)&hbuf[rp][kf * 16 + quad * 4];
      }
      floatx4 a0, a1, a2, a3;
      {
        half8v hb = __builtin_bit_cast(half8v, hfr[0]);
        a0 = __builtin_amdgcn_mfma_f32_16x16x32_f16(
                 __builtin_bit_cast(half8v, wa[0][0]), hb, zf, 0, 0, 0);
        a1 = __builtin_amdgcn_mfma_f32_16x16x32_f16(
                 __builtin_bit_cast(half8v, wa[1][0]), hb, zf, 0, 0, 0);
        a2 = __builtin_amdgcn_mfma_f32_16x16x32_f16(
                 __builtin_bit_cast(half8v, wa[2][0]), hb, zf, 0, 0, 0);
        a3 = __builtin_amdgcn_mfma_f32_16x16x32_f16(
                 __builtin_bit_cast(half8v, wa[3][0]), hb, zf, 0, 0, 0);
      }
      #pragma unroll
      for (int kf = 1; kf < 4; ++kf) {
        half8v hb = __builtin_bit_cast(half8v, hfr[kf]);
        a0 = __builtin_amdgcn_mfma_f32_16x16x32_f16(
                 __builtin_bit_cast(half8v, wa[0][kf]), hb, a0, 0, 0, 0);
        a1 = __builtin_amdgcn_mfma_f32_16x16x32_f16(
                 __builtin_bit_cast(half8v, wa[1][kf]), hb, a1, 0, 0, 0);
        a2 = __builtin_amdgcn_mfma_f32_16x16x32_f16(
                 __builtin_bit_cast(half8v, wa[2][kf]), hb, a2, 0, 0, 0);
        a3 = __builtin_amdgcn_mfma_f32_16x16x32_f16(
                 __builtin_bit_cast(half8v, wa[3][kf]), hb, a3, 0, 0, 0);
      }
      if (m16 < 4) {
        const int n  = m16;
        const int jl = wv * 16 + quad * 4 + n;
        unsigned xlo = (unsigned)xv, xhi = (unsigned)(xv >> 32);
        float pi = SEL4(a0, n) + h2f_lo(xlo);
        float pf = SEL4(a1, n) + h2f_hi(xlo);
        float pg = SEL4(a2, n) + h2f_lo(xhi);
        float po = SEL4(a3, n) + h2f_hi(xhi);
        float gi = __builtin_amdgcn_rcpf(1.0f + __builtin_amdgcn_exp2f(pi));
        float gf = __builtin_amdgcn_rcpf(1.0f + __builtin_amdgcn_exp2f(pf));
        float go = __builtin_amdgcn_rcpf(1.0f + __builtin_amdgcn_exp2f(po));
        float gg = 1.0f - 2.0f * __builtin_amdgcn_rcpf(1.0f + __builtin_amdgcn_exp2f(pg));
        c = gf * c + gi * gg;
        float tc = 1.0f - 2.0f * __builtin_amdgcn_rcpf(
                       1.0f + __builtin_amdgcn_exp2f(c * LOG2E2));
        float h = go * tc;
        ((unsigned short*)hbuf[rp ^ 1])[jl] = __half_as_ushort(__float2half(h));
      }
      __syncthreads();
    }
  }

  // ---- out = h_last @ Wo^T + bo   (h_last in hbuf[0]: last step wrote buf 0)
  if (tid < H_) {
    float acc = bo[tid];
    const float4* wr = (const float4*)(Wo + (size_t)tid * H_);
    const uint2* hp = (const uint2*)hbuf[0];
    #pragma unroll
    for (int k4 = 0; k4 < 32; ++k4) {
      float4 w  = wr[k4];
      uint2  hu = hp[k4];
      acc += w.x * h2f_lo(hu.x) + w.y * h2f_hi(hu.x)
           + w.z * h2f_lo(hu.y) + w.w * h2f_hi(hu.y);
    }
    out[(size_t)b * H_ + tid] = acc;
  }
}

extern "C" void kernel_launch(void* const* d_in, const int* in_sizes, int n_in,
                              void* d_out, int out_size, void* d_ws, size_t ws_size,
                              hipStream_t stream) {
  (void)in_sizes; (void)n_in; (void)d_ws; (void)ws_size; (void)out_size;
  const float* x   = (const float*)d_in[0];
  const float* Wih = (const float*)d_in[1];
  const float* Whh = (const float*)d_in[2];
  const float* bih = (const float*)d_in[3];
  const float* bhh = (const float*)d_in[4];
  const float* Wo  = (const float*)d_in[5];
  const float* bo  = (const float*)d_in[6];
  lstm_mfma3<<<B_, 512, 0, stream>>>(x, Wih, Whh, bih, bhh, Wo, bo, (float*)d_out);
}